// Round 6
// baseline (713.709 us; speedup 1.0000x reference)
//
#include <hip/hip_runtime.h>
#include <math.h>

// ---------------------------------------------------------------------------
// GCN link predictor on MI355X, round 6.
// Round-5 post-mortem: feature slices thrashed because (a) every XCD touched
// every slice (refill per phase), (b) CSR/output streams evicted the resident
// set. Round 6: XCD-PINNED slices (blockIdx&7 -> XCD round-robin heuristic;
// slice==xcd) + non-temporal loads for CSR/offs + NT stores for output.
// Layer1: 8 slices x 16 feats (1.6MB resident/XCD). Layer2: 4 slices x 16.
// ---------------------------------------------------------------------------

typedef __attribute__((ext_vector_type(8))) short short8x;
typedef __attribute__((ext_vector_type(4))) float f32x4;

__device__ __forceinline__ unsigned short f2bf(float f) {
  unsigned int u = __float_as_uint(f);
  unsigned int r = u + 0x7FFFu + ((u >> 16) & 1u);  // RNE
  return (unsigned short)(r >> 16);
}
__device__ __forceinline__ float bf2f(unsigned short u) {
  return __uint_as_float(((unsigned int)u) << 16);
}

// ------------------------------ graph build --------------------------------

__global__ void zero_int_kernel(int* __restrict__ p, int n) {
  int i = blockIdx.x * blockDim.x + threadIdx.x;
  if (i < n) p[i] = 0;
}

__global__ void degree_hist_kernel(const int* __restrict__ col, int* __restrict__ deg, int E) {
  int i = blockIdx.x * blockDim.x + threadIdx.x;
  if (i < E) atomicAdd(&deg[col[i]], 1);
}

__global__ __launch_bounds__(256) void scan_blocksum_kernel(const int* __restrict__ deg,
                                                            int* __restrict__ bsum, int n) {
  __shared__ int ws[4];
  int base = blockIdx.x * 1024;
  int tid = threadIdx.x;
  int s = 0;
#pragma unroll
  for (int j = 0; j < 4; ++j) {
    int i = base + tid + j * 256;
    if (i < n) s += deg[i];
  }
#pragma unroll
  for (int d = 1; d < 64; d <<= 1) s += __shfl_xor(s, d, 64);
  if ((tid & 63) == 0) ws[tid >> 6] = s;
  __syncthreads();
  if (tid == 0) bsum[blockIdx.x] = ws[0] + ws[1] + ws[2] + ws[3];
}

__global__ __launch_bounds__(64) void scan_bsum_kernel(int* __restrict__ bsum, int nb,
                                                       int* __restrict__ total) {
  int lane = threadIdx.x;
  int v = (lane < nb) ? bsum[lane] : 0;
  int incl = v;
#pragma unroll
  for (int d = 1; d < 64; d <<= 1) {
    int t = __shfl_up(incl, d, 64);
    if (lane >= d) incl += t;
  }
  if (lane < nb) bsum[lane] = incl - v;
  if (lane == 63) *total = incl;
}

__global__ __launch_bounds__(256) void scan_final_kernel(const int* __restrict__ deg,
                                                         const int* __restrict__ bsum,
                                                         int* __restrict__ offs,
                                                         float* __restrict__ dinv, int n) {
  __shared__ int wsum[4];
  int tid = threadIdx.x;
  int lane = tid & 63;
  int wid = tid >> 6;
  int idx0 = blockIdx.x * 1024 + tid * 4;
  int v[4];
#pragma unroll
  for (int j = 0; j < 4; ++j) {
    int i = idx0 + j;
    v[j] = (i < n) ? deg[i] : 0;
  }
  int tsum = v[0] + v[1] + v[2] + v[3];
  int incl = tsum;
#pragma unroll
  for (int d = 1; d < 64; d <<= 1) {
    int t = __shfl_up(incl, d, 64);
    if (lane >= d) incl += t;
  }
  if (lane == 63) wsum[wid] = incl;
  __syncthreads();
  int woff = 0;
#pragma unroll
  for (int w = 0; w < 4; ++w)
    if (w < wid) woff += wsum[w];
  int run = woff + incl - tsum + bsum[blockIdx.x];
#pragma unroll
  for (int j = 0; j < 4; ++j) {
    int i = idx0 + j;
    if (i < n) {
      offs[i] = run;
      dinv[i] = rsqrtf((float)v[j] + 1.0f);
      run += v[j];
    }
  }
}

__global__ void bucket_init_kernel(const int* __restrict__ offs, const int* __restrict__ total,
                                   int* __restrict__ bcur, int* __restrict__ offs_n, int NBK) {
  int b = blockIdx.x * blockDim.x + threadIdx.x;
  if (b < NBK) bcur[b] = offs[b * 256];
  if (b == 0) *offs_n = *total;
}

// binA: 4096 edges/block; LDS hist -> one global atomicAdd per (block,bucket)
// -> LDS-cursor scatter of packed (col<<16|row).
__global__ __launch_bounds__(256) void binA_kernel(const int* __restrict__ row,
                                                   const int* __restrict__ col,
                                                   int* __restrict__ bcur,
                                                   unsigned int* __restrict__ staging, int E,
                                                   int NBK) {
  __shared__ int hist[256];
  const int tid = threadIdx.x;
  hist[tid] = 0;
  __syncthreads();
  const int base = blockIdx.x * 4096;
  unsigned int payload[16];
  int bk[16];
#pragma unroll
  for (int j = 0; j < 16; ++j) {
    int i = base + j * 256 + tid;
    if (i < E) {
      unsigned int c = (unsigned int)col[i];
      unsigned int r = (unsigned int)row[i];
      payload[j] = (c << 16) | r;
      bk[j] = (int)(c >> 8);
      atomicAdd(&hist[bk[j]], 1);
    } else {
      bk[j] = -1;
    }
  }
  __syncthreads();
  if (tid < NBK) {
    int h = hist[tid];
    hist[tid] = h ? atomicAdd(&bcur[tid], h) : 0;
  }
  __syncthreads();
#pragma unroll
  for (int j = 0; j < 16; ++j) {
    if (bk[j] >= 0) {
      int p = atomicAdd(&hist[bk[j]], 1);
      staging[p] = payload[j];
    }
  }
}

// binB: one block per 256-node bucket; per-node LDS cursors; CSR entry =
// bf16(dinv[row])<<16 | row.
__global__ __launch_bounds__(512) void binB_kernel(const unsigned int* __restrict__ staging,
                                                   const int* __restrict__ offs,
                                                   const float* __restrict__ dinv,
                                                   unsigned int* __restrict__ csr, int N) {
  __shared__ int cur[256];
  const int b = blockIdx.x;
  const int n0 = b * 256;
  const int nn = min(256, N - n0);
  const int tid = threadIdx.x;
  if (tid < nn) cur[tid] = offs[n0 + tid];
  __syncthreads();
  const int s = offs[n0];
  const int e = offs[min(n0 + 256, N)];
  for (int t = s + tid; t < e; t += 512) {
    unsigned int v = __builtin_nontemporal_load(&staging[t]);
    int cl = (int)((v >> 16) & 255u);
    unsigned int r = v & 0xFFFFu;
    unsigned int wd = f2bf(dinv[r]);
    int p = atomicAdd(&cur[cl], 1);
    csr[p] = (wd << 16) | r;
  }
}

// --------------------- weight prep: fragment ordering ----------------------
__global__ void prep_bfrag_kernel(const float* __restrict__ W, unsigned short* __restrict__ out,
                                  int K, int N) {
  int idx = blockIdx.x * blockDim.x + threadIdx.x;
  int KS = K / 32;
  int total = (N / 16) * KS * 64;
  if (idx >= total) return;
  int lane = idx & 63;
  int t = idx >> 6;
  int ks = t % KS;
  int nt = t / KS;
  int n = nt * 16 + (lane & 15);
  int k0 = ks * 32 + (lane >> 4) * 8;
  unsigned short* o = out + (size_t)idx * 8;
#pragma unroll
  for (int j = 0; j < 8; ++j) o[j] = f2bf(W[(size_t)(k0 + j) * N + n]);
}

// ------------------------------- MFMA GEMM ---------------------------------
template <int K, int N, bool ABF16>
__global__ __launch_bounds__(256) void mfma_gemm_kernel(const void* __restrict__ Ap,
                                                        const unsigned short* __restrict__ Bfrag,
                                                        unsigned short* __restrict__ Cout, int M) {
  constexpr int KS = K / 32;
  constexpr int NT = N / 16;
  const int lane = threadIdx.x & 63;
  const int wid = threadIdx.x >> 6;
  const int quad = lane >> 4;
  const int lc = lane & 15;
  const int mbase = blockIdx.x * 128 + wid * 32;
  if (mbase >= M) return;

  f32x4 acc[2][NT];
#pragma unroll
  for (int mt = 0; mt < 2; ++mt)
#pragma unroll
    for (int nt = 0; nt < NT; ++nt) acc[mt][nt] = (f32x4){0.f, 0.f, 0.f, 0.f};

  int r0 = mbase + lc;
  int r1 = mbase + 16 + lc;
  if (r0 >= M) r0 = M - 1;
  if (r1 >= M) r1 = M - 1;

#pragma unroll
  for (int ks = 0; ks < KS; ++ks) {
    const int k0 = ks * 32 + quad * 8;
    short8x a[2];
    if constexpr (ABF16) {
      const unsigned short* A = (const unsigned short*)Ap;
      a[0] = *(const short8x*)(A + (size_t)r0 * K + k0);
      a[1] = *(const short8x*)(A + (size_t)r1 * K + k0);
    } else {
      const float* A = (const float*)Ap;
      const float4* p0 = (const float4*)(A + (size_t)r0 * K + k0);
      const float4* p1 = (const float4*)(A + (size_t)r1 * K + k0);
      float4 u0 = p0[0], v0 = p0[1];
      float4 u1 = p1[0], v1 = p1[1];
      short8x t0, t1;
      t0[0] = (short)f2bf(u0.x); t0[1] = (short)f2bf(u0.y);
      t0[2] = (short)f2bf(u0.z); t0[3] = (short)f2bf(u0.w);
      t0[4] = (short)f2bf(v0.x); t0[5] = (short)f2bf(v0.y);
      t0[6] = (short)f2bf(v0.z); t0[7] = (short)f2bf(v0.w);
      t1[0] = (short)f2bf(u1.x); t1[1] = (short)f2bf(u1.y);
      t1[2] = (short)f2bf(u1.z); t1[3] = (short)f2bf(u1.w);
      t1[4] = (short)f2bf(v1.x); t1[5] = (short)f2bf(v1.y);
      t1[6] = (short)f2bf(v1.z); t1[7] = (short)f2bf(v1.w);
      a[0] = t0;
      a[1] = t1;
    }
#pragma unroll
    for (int nt = 0; nt < NT; ++nt) {
      short8x b = *(const short8x*)(Bfrag + (((size_t)nt * KS + ks) * 64 + lane) * 8);
      acc[0][nt] = __builtin_amdgcn_mfma_f32_16x16x32_bf16(a[0], b, acc[0][nt], 0, 0, 0);
      acc[1][nt] = __builtin_amdgcn_mfma_f32_16x16x32_bf16(a[1], b, acc[1][nt], 0, 0, 0);
    }
  }

#pragma unroll
  for (int mt = 0; mt < 2; ++mt)
#pragma unroll
    for (int nt = 0; nt < NT; ++nt)
#pragma unroll
      for (int reg = 0; reg < 4; ++reg) {
        int row = mbase + mt * 16 + quad * 4 + reg;
        if (row < M) Cout[(size_t)row * N + nt * 16 + lc] = f2bf(acc[mt][nt][reg]);
      }
}

// ------------------- aggregation (XCD-pinned feature slices) ---------------
// blockIdx.x -> XCD via &7 round-robin (perf heuristic only). slice = low
// bits of blockIdx -> each XCD keeps ONE 16-feat slice (N*16*2B = 1.6MB)
// resident in its L2. CSR/offs read non-temporally; output stored NT, so
// streams don't evict the resident gather set. Block = 256 thr = 16 nodes
// x 16 feats. LOG2SL=3 -> 8 slices (F=128); LOG2SL=2 -> 4 slices (F=64).
template <int F, int LOG2SL>
__global__ __launch_bounds__(256) void agg_swz_kernel(
    const unsigned short* __restrict__ xw, const int* __restrict__ offs,
    const unsigned int* __restrict__ csr, const float* __restrict__ dinv,
    const float* __restrict__ bias, const float* __restrict__ gamma,
    const float* __restrict__ beta, const float* __restrict__ mean,
    const float* __restrict__ var, unsigned short* __restrict__ out, int N) {
  const unsigned int b = blockIdx.x;
  const int slice = b & ((1 << LOG2SL) - 1);
  const int chunk = b >> LOG2SL;
  const int nsub = threadIdx.x >> 4;  // node within block (0..15)
  const int i = chunk * 16 + nsub;
  if (i >= N) return;
  const int f = slice * 16 + (threadIdx.x & 15);
  const float di = dinv[i];
  const int s = __builtin_nontemporal_load(&offs[i]);
  const int e = __builtin_nontemporal_load(&offs[i + 1]);
  float acc = 0.f;
  int t = s;
  for (; t + 4 <= e; t += 4) {
    unsigned int e0 = __builtin_nontemporal_load(&csr[t]);
    unsigned int e1 = __builtin_nontemporal_load(&csr[t + 1]);
    unsigned int e2 = __builtin_nontemporal_load(&csr[t + 2]);
    unsigned int e3 = __builtin_nontemporal_load(&csr[t + 3]);
    acc += bf2f(e0 >> 16) * bf2f(xw[(size_t)(e0 & 0xFFFFu) * F + f]) +
           bf2f(e1 >> 16) * bf2f(xw[(size_t)(e1 & 0xFFFFu) * F + f]) +
           bf2f(e2 >> 16) * bf2f(xw[(size_t)(e2 & 0xFFFFu) * F + f]) +
           bf2f(e3 >> 16) * bf2f(xw[(size_t)(e3 & 0xFFFFu) * F + f]);
  }
  for (; t < e; ++t) {
    unsigned int e0 = __builtin_nontemporal_load(&csr[t]);
    acc += bf2f(e0 >> 16) * bf2f(xw[(size_t)(e0 & 0xFFFFu) * F + f]);
  }
  float v = di * acc + di * di * bf2f(xw[(size_t)i * F + f]) + bias[f];
  v = (v - mean[f]) * rsqrtf(var[f] + 1e-5f) * gamma[f] + beta[f];
  __builtin_nontemporal_store(f2bf(fmaxf(v, 0.f)), &out[(size_t)i * F + f]);
}

// ------------------------------- edge head ---------------------------------
__global__ __launch_bounds__(256) void head_mfma_kernel(
    const unsigned short* __restrict__ z, const int* __restrict__ src,
    const int* __restrict__ dst, const unsigned short* __restrict__ bfragH,
    const float* __restrict__ hb1, const float* __restrict__ hw2,
    const float* __restrict__ hb2, float* __restrict__ out, int P) {
  const int lane = threadIdx.x & 63;
  const int quad = lane >> 4;
  const int lc = lane & 15;

  short8x bf[4][4];
#pragma unroll
  for (int nt = 0; nt < 4; ++nt)
#pragma unroll
    for (int ks = 0; ks < 4; ++ks)
      bf[nt][ks] = *(const short8x*)(bfragH + (((size_t)nt * 4 + ks) * 64 + lane) * 8);

  float b1v[4], w2v[4];
#pragma unroll
  for (int nt = 0; nt < 4; ++nt) {
    b1v[nt] = hb1[nt * 16 + lc];
    w2v[nt] = hw2[nt * 16 + lc];
  }
  const float bias2 = hb2[0];

  const int nchunks = (P + 15) / 16;
  const int gw = blockIdx.x * 4 + (threadIdx.x >> 6);
  const int nw = gridDim.x * 4;

  for (int ch = gw; ch < nchunks; ch += nw) {
    int p = ch * 16 + lc;
    int pc = p < P ? p : P - 1;
    int s = src[pc], d = dst[pc];
    const unsigned short* zs = z + (size_t)s * 64;
    const unsigned short* zd = z + (size_t)d * 64;
    short8x a[4];
    a[0] = *(const short8x*)(zs + quad * 8);
    a[1] = *(const short8x*)(zs + 32 + quad * 8);
    a[2] = *(const short8x*)(zd + quad * 8);
    a[3] = *(const short8x*)(zd + 32 + quad * 8);

    f32x4 acc[4];
#pragma unroll
    for (int nt = 0; nt < 4; ++nt) acc[nt] = (f32x4){0.f, 0.f, 0.f, 0.f};
#pragma unroll
    for (int nt = 0; nt < 4; ++nt)
#pragma unroll
      for (int t = 0; t < 4; ++t)
        acc[nt] = __builtin_amdgcn_mfma_f32_16x16x32_bf16(a[t], bf[nt][t], acc[nt], 0, 0, 0);

    float part[4];
#pragma unroll
    for (int reg = 0; reg < 4; ++reg) {
      float sum = 0.f;
#pragma unroll
      for (int nt = 0; nt < 4; ++nt) sum += fmaxf(acc[nt][reg] + b1v[nt], 0.f) * w2v[nt];
      part[reg] = sum;
    }
#pragma unroll
    for (int m = 1; m < 16; m <<= 1) {
#pragma unroll
      for (int reg = 0; reg < 4; ++reg) part[reg] += __shfl_xor(part[reg], m, 64);
    }
    if (lc == 0) {
      int pbase = ch * 16 + quad * 4;
      float4 o;
      o.x = 1.0f / (1.0f + __expf(-(part[0] + bias2)));
      o.y = 1.0f / (1.0f + __expf(-(part[1] + bias2)));
      o.z = 1.0f / (1.0f + __expf(-(part[2] + bias2)));
      o.w = 1.0f / (1.0f + __expf(-(part[3] + bias2)));
      if (pbase + 3 < P) {
        *(float4*)(out + pbase) = o;
      } else {
        float ov[4] = {o.x, o.y, o.z, o.w};
        for (int reg = 0; reg < 4; ++reg)
          if (pbase + reg < P) out[pbase + reg] = ov[reg];
      }
    }
  }
}

// ------------------------------- launcher ----------------------------------

extern "C" void kernel_launch(void* const* d_in, const int* in_sizes, int n_in,
                              void* d_out, int out_size, void* d_ws, size_t ws_size,
                              hipStream_t stream) {
  const float* x = (const float*)d_in[0];
  const int* ei = (const int*)d_in[1];
  const int* src = (const int*)d_in[2];
  const int* dst = (const int*)d_in[3];
  const float* W1 = (const float*)d_in[4];
  const float* b1 = (const float*)d_in[5];
  const float* g1 = (const float*)d_in[6];
  const float* be1 = (const float*)d_in[7];
  const float* mu1 = (const float*)d_in[8];
  const float* va1 = (const float*)d_in[9];
  const float* W2 = (const float*)d_in[10];
  const float* b2 = (const float*)d_in[11];
  const float* g2 = (const float*)d_in[12];
  const float* be2 = (const float*)d_in[13];
  const float* mu2 = (const float*)d_in[14];
  const float* va2 = (const float*)d_in[15];
  const float* hW1 = (const float*)d_in[16];
  const float* hb1 = (const float*)d_in[17];
  const float* hW2 = (const float*)d_in[18];
  const float* hb2 = (const float*)d_in[19];
  float* out = (float*)d_out;

  const int N = in_sizes[0] / 512;
  const int E = in_sizes[1] / 2;
  const int P = in_sizes[2];
  const int* row = ei;
  const int* col = ei + E;
  const int NBK = (N + 255) / 256;    // scatter buckets (256 nodes each)
  const int NSB = (N + 1023) / 1024;  // scan blocks
  const int NAB = (E + 4095) / 4096;  // binA blocks
  const int NCH = (N + 15) / 16;      // agg node chunks

  char* wp = (char*)d_ws;
  auto alloc = [&](size_t bytes) {
    char* p = wp;
    wp += (bytes + 255) & ~(size_t)255;
    return p;
  };
  unsigned short* xw1 = (unsigned short*)alloc((size_t)N * 128 * 2);
  unsigned short* h = (unsigned short*)alloc((size_t)N * 128 * 2);
  unsigned short* xw2 = (unsigned short*)alloc((size_t)N * 64 * 2);
  unsigned short* z = (unsigned short*)alloc((size_t)N * 64 * 2);
  float* dinv = (float*)alloc((size_t)N * 4);
  int* deg = (int*)alloc((size_t)N * 4);
  int* offs = (int*)alloc((size_t)(N + 1) * 4);
  unsigned int* csr = (unsigned int*)alloc((size_t)E * 4);
  unsigned int* staging = (unsigned int*)alloc((size_t)E * 4);
  int* bsum = (int*)alloc((size_t)NSB * 4);
  int* bcur = (int*)alloc((size_t)NBK * 4);
  int* total = (int*)alloc(256);
  unsigned short* bfW1 = (unsigned short*)alloc(512 * 128 * 2);
  unsigned short* bfW2 = (unsigned short*)alloc(128 * 64 * 2);
  unsigned short* bfH = (unsigned short*)alloc(128 * 64 * 2);
  (void)ws_size;
  (void)n_in;
  (void)out_size;

  // --- graph structure ---
  hipLaunchKernelGGL(zero_int_kernel, dim3((N + 255) / 256), dim3(256), 0, stream, deg, N);
  hipLaunchKernelGGL(degree_hist_kernel, dim3((E + 255) / 256), dim3(256), 0, stream, col, deg, E);
  hipLaunchKernelGGL(scan_blocksum_kernel, dim3(NSB), dim3(256), 0, stream, deg, bsum, N);
  hipLaunchKernelGGL(scan_bsum_kernel, dim3(1), dim3(64), 0, stream, bsum, NSB, total);
  hipLaunchKernelGGL(scan_final_kernel, dim3(NSB), dim3(256), 0, stream, deg, bsum, offs, dinv, N);
  hipLaunchKernelGGL(bucket_init_kernel, dim3((NBK + 255) / 256), dim3(256), 0, stream, offs, total,
                     bcur, offs + N, NBK);
  hipLaunchKernelGGL(binA_kernel, dim3(NAB), dim3(256), 0, stream, row, col, bcur, staging, E, NBK);
  hipLaunchKernelGGL(binB_kernel, dim3(NBK), dim3(512), 0, stream, staging, offs, dinv, csr, N);

  // --- weight fragment prep ---
  hipLaunchKernelGGL(prep_bfrag_kernel, dim3((8 * 16 * 64 + 255) / 256), dim3(256), 0, stream, W1,
                     bfW1, 512, 128);
  hipLaunchKernelGGL(prep_bfrag_kernel, dim3((4 * 4 * 64 + 255) / 256), dim3(256), 0, stream, W2,
                     bfW2, 128, 64);
  hipLaunchKernelGGL(prep_bfrag_kernel, dim3((4 * 4 * 64 + 255) / 256), dim3(256), 0, stream, hW1,
                     bfH, 128, 64);

  // --- layer 1 ---
  hipLaunchKernelGGL((mfma_gemm_kernel<512, 128, false>), dim3((N + 127) / 128), dim3(256), 0,
                     stream, x, bfW1, xw1, N);
  hipLaunchKernelGGL((agg_swz_kernel<128, 3>), dim3(NCH * 8), dim3(256), 0, stream, xw1, offs, csr,
                     dinv, b1, g1, be1, mu1, va1, h, N);

  // --- layer 2 ---
  hipLaunchKernelGGL((mfma_gemm_kernel<128, 64, true>), dim3((N + 127) / 128), dim3(256), 0, stream,
                     h, bfW2, xw2, N);
  hipLaunchKernelGGL((agg_swz_kernel<64, 2>), dim3(NCH * 4), dim3(256), 0, stream, xw2, offs, csr,
                     dinv, b2, g2, be2, mu2, va2, z, N);

  // --- edge head ---
  hipLaunchKernelGGL(head_mfma_kernel, dim3(2048), dim3(256), 0, stream, z, src, dst, bfH, hb1,
                     hW2, hb2, out, P);
}

// Round 7
// 439.055 us; speedup vs baseline: 1.6256x; 1.6256x over previous
//
#include <hip/hip_runtime.h>
#include <math.h>

// ---------------------------------------------------------------------------
// GCN link predictor on MI355X, round 7.
// Rounds 5/6 falsified L2-slicing (XCD pinning doesn't hold; pass-count
// multiplies misses). Round 4 agg was LATENCY-bound (2.4 TB/s effective with
// 77% occupancy + 29% VALU): only ~8 lines in flight per wave. Round 7 =
// round-4 structure + 16-deep edge batching (load 16 CSR entries, issue 16
// independent row gathers, then accumulate), dword-per-lane (2 bf16 feats).
// ---------------------------------------------------------------------------

typedef __attribute__((ext_vector_type(8))) short short8x;
typedef __attribute__((ext_vector_type(4))) float f32x4;

__device__ __forceinline__ unsigned short f2bf(float f) {
  unsigned int u = __float_as_uint(f);
  unsigned int r = u + 0x7FFFu + ((u >> 16) & 1u);  // RNE
  return (unsigned short)(r >> 16);
}
__device__ __forceinline__ float bf2f(unsigned short u) {
  return __uint_as_float(((unsigned int)u) << 16);
}

// ------------------------------ graph build --------------------------------

__global__ void zero_int_kernel(int* __restrict__ p, int n) {
  int i = blockIdx.x * blockDim.x + threadIdx.x;
  if (i < n) p[i] = 0;
}

__global__ void degree_hist_kernel(const int* __restrict__ col, int* __restrict__ deg, int E) {
  int i = blockIdx.x * blockDim.x + threadIdx.x;
  if (i < E) atomicAdd(&deg[col[i]], 1);
}

__global__ __launch_bounds__(256) void scan_blocksum_kernel(const int* __restrict__ deg,
                                                            int* __restrict__ bsum, int n) {
  __shared__ int ws[4];
  int base = blockIdx.x * 1024;
  int tid = threadIdx.x;
  int s = 0;
#pragma unroll
  for (int j = 0; j < 4; ++j) {
    int i = base + tid + j * 256;
    if (i < n) s += deg[i];
  }
#pragma unroll
  for (int d = 1; d < 64; d <<= 1) s += __shfl_xor(s, d, 64);
  if ((tid & 63) == 0) ws[tid >> 6] = s;
  __syncthreads();
  if (tid == 0) bsum[blockIdx.x] = ws[0] + ws[1] + ws[2] + ws[3];
}

__global__ __launch_bounds__(64) void scan_bsum_kernel(int* __restrict__ bsum, int nb,
                                                       int* __restrict__ total) {
  int lane = threadIdx.x;
  int v = (lane < nb) ? bsum[lane] : 0;
  int incl = v;
#pragma unroll
  for (int d = 1; d < 64; d <<= 1) {
    int t = __shfl_up(incl, d, 64);
    if (lane >= d) incl += t;
  }
  if (lane < nb) bsum[lane] = incl - v;
  if (lane == 63) *total = incl;
}

__global__ __launch_bounds__(256) void scan_final_kernel(const int* __restrict__ deg,
                                                         const int* __restrict__ bsum,
                                                         int* __restrict__ offs,
                                                         float* __restrict__ dinv, int n) {
  __shared__ int wsum[4];
  int tid = threadIdx.x;
  int lane = tid & 63;
  int wid = tid >> 6;
  int idx0 = blockIdx.x * 1024 + tid * 4;
  int v[4];
#pragma unroll
  for (int j = 0; j < 4; ++j) {
    int i = idx0 + j;
    v[j] = (i < n) ? deg[i] : 0;
  }
  int tsum = v[0] + v[1] + v[2] + v[3];
  int incl = tsum;
#pragma unroll
  for (int d = 1; d < 64; d <<= 1) {
    int t = __shfl_up(incl, d, 64);
    if (lane >= d) incl += t;
  }
  if (lane == 63) wsum[wid] = incl;
  __syncthreads();
  int woff = 0;
#pragma unroll
  for (int w = 0; w < 4; ++w)
    if (w < wid) woff += wsum[w];
  int run = woff + incl - tsum + bsum[blockIdx.x];
#pragma unroll
  for (int j = 0; j < 4; ++j) {
    int i = idx0 + j;
    if (i < n) {
      offs[i] = run;
      dinv[i] = rsqrtf((float)v[j] + 1.0f);
      run += v[j];
    }
  }
}

__global__ void bucket_init_kernel(const int* __restrict__ offs, const int* __restrict__ total,
                                   int* __restrict__ bcur, int* __restrict__ offs_n, int NBK) {
  int b = blockIdx.x * blockDim.x + threadIdx.x;
  if (b < NBK) bcur[b] = offs[b * 256];
  if (b == 0) *offs_n = *total;
}

// binA: 4096 edges/block; LDS hist -> one global atomicAdd per (block,bucket)
// -> LDS-cursor scatter of packed (col<<16|row).
__global__ __launch_bounds__(256) void binA_kernel(const int* __restrict__ row,
                                                   const int* __restrict__ col,
                                                   int* __restrict__ bcur,
                                                   unsigned int* __restrict__ staging, int E,
                                                   int NBK) {
  __shared__ int hist[256];
  const int tid = threadIdx.x;
  hist[tid] = 0;
  __syncthreads();
  const int base = blockIdx.x * 4096;
  unsigned int payload[16];
  int bk[16];
#pragma unroll
  for (int j = 0; j < 16; ++j) {
    int i = base + j * 256 + tid;
    if (i < E) {
      unsigned int c = (unsigned int)col[i];
      unsigned int r = (unsigned int)row[i];
      payload[j] = (c << 16) | r;
      bk[j] = (int)(c >> 8);
      atomicAdd(&hist[bk[j]], 1);
    } else {
      bk[j] = -1;
    }
  }
  __syncthreads();
  if (tid < NBK) {
    int h = hist[tid];
    hist[tid] = h ? atomicAdd(&bcur[tid], h) : 0;
  }
  __syncthreads();
#pragma unroll
  for (int j = 0; j < 16; ++j) {
    if (bk[j] >= 0) {
      int p = atomicAdd(&hist[bk[j]], 1);
      staging[p] = payload[j];
    }
  }
}

// binB: one block per 256-node bucket; per-node LDS cursors; CSR entry =
// bf16(dinv[row])<<16 | row.
__global__ __launch_bounds__(512) void binB_kernel(const unsigned int* __restrict__ staging,
                                                   const int* __restrict__ offs,
                                                   const float* __restrict__ dinv,
                                                   unsigned int* __restrict__ csr, int N) {
  __shared__ int cur[256];
  const int b = blockIdx.x;
  const int n0 = b * 256;
  const int nn = min(256, N - n0);
  const int tid = threadIdx.x;
  if (tid < nn) cur[tid] = offs[n0 + tid];
  __syncthreads();
  const int s = offs[n0];
  const int e = offs[min(n0 + 256, N)];
  for (int t = s + tid; t < e; t += 512) {
    unsigned int v = __builtin_nontemporal_load(&staging[t]);
    int cl = (int)((v >> 16) & 255u);
    unsigned int r = v & 0xFFFFu;
    unsigned int wd = f2bf(dinv[r]);
    int p = atomicAdd(&cur[cl], 1);
    csr[p] = (wd << 16) | r;
  }
}

// --------------------- weight prep: fragment ordering ----------------------
__global__ void prep_bfrag_kernel(const float* __restrict__ W, unsigned short* __restrict__ out,
                                  int K, int N) {
  int idx = blockIdx.x * blockDim.x + threadIdx.x;
  int KS = K / 32;
  int total = (N / 16) * KS * 64;
  if (idx >= total) return;
  int lane = idx & 63;
  int t = idx >> 6;
  int ks = t % KS;
  int nt = t / KS;
  int n = nt * 16 + (lane & 15);
  int k0 = ks * 32 + (lane >> 4) * 8;
  unsigned short* o = out + (size_t)idx * 8;
#pragma unroll
  for (int j = 0; j < 8; ++j) o[j] = f2bf(W[(size_t)(k0 + j) * N + n]);
}

// ------------------------------- MFMA GEMM ---------------------------------
template <int K, int N, bool ABF16>
__global__ __launch_bounds__(256) void mfma_gemm_kernel(const void* __restrict__ Ap,
                                                        const unsigned short* __restrict__ Bfrag,
                                                        unsigned short* __restrict__ Cout, int M) {
  constexpr int KS = K / 32;
  constexpr int NT = N / 16;
  const int lane = threadIdx.x & 63;
  const int wid = threadIdx.x >> 6;
  const int quad = lane >> 4;
  const int lc = lane & 15;
  const int mbase = blockIdx.x * 128 + wid * 32;
  if (mbase >= M) return;

  f32x4 acc[2][NT];
#pragma unroll
  for (int mt = 0; mt < 2; ++mt)
#pragma unroll
    for (int nt = 0; nt < NT; ++nt) acc[mt][nt] = (f32x4){0.f, 0.f, 0.f, 0.f};

  int r0 = mbase + lc;
  int r1 = mbase + 16 + lc;
  if (r0 >= M) r0 = M - 1;
  if (r1 >= M) r1 = M - 1;

#pragma unroll
  for (int ks = 0; ks < KS; ++ks) {
    const int k0 = ks * 32 + quad * 8;
    short8x a[2];
    if constexpr (ABF16) {
      const unsigned short* A = (const unsigned short*)Ap;
      a[0] = *(const short8x*)(A + (size_t)r0 * K + k0);
      a[1] = *(const short8x*)(A + (size_t)r1 * K + k0);
    } else {
      const float* A = (const float*)Ap;
      const float4* p0 = (const float4*)(A + (size_t)r0 * K + k0);
      const float4* p1 = (const float4*)(A + (size_t)r1 * K + k0);
      float4 u0 = p0[0], v0 = p0[1];
      float4 u1 = p1[0], v1 = p1[1];
      short8x t0, t1;
      t0[0] = (short)f2bf(u0.x); t0[1] = (short)f2bf(u0.y);
      t0[2] = (short)f2bf(u0.z); t0[3] = (short)f2bf(u0.w);
      t0[4] = (short)f2bf(v0.x); t0[5] = (short)f2bf(v0.y);
      t0[6] = (short)f2bf(v0.z); t0[7] = (short)f2bf(v0.w);
      t1[0] = (short)f2bf(u1.x); t1[1] = (short)f2bf(u1.y);
      t1[2] = (short)f2bf(u1.z); t1[3] = (short)f2bf(u1.w);
      t1[4] = (short)f2bf(v1.x); t1[5] = (short)f2bf(v1.y);
      t1[6] = (short)f2bf(v1.z); t1[7] = (short)f2bf(v1.w);
      a[0] = t0;
      a[1] = t1;
    }
#pragma unroll
    for (int nt = 0; nt < NT; ++nt) {
      short8x b = *(const short8x*)(Bfrag + (((size_t)nt * KS + ks) * 64 + lane) * 8);
      acc[0][nt] = __builtin_amdgcn_mfma_f32_16x16x32_bf16(a[0], b, acc[0][nt], 0, 0, 0);
      acc[1][nt] = __builtin_amdgcn_mfma_f32_16x16x32_bf16(a[1], b, acc[1][nt], 0, 0, 0);
    }
  }

#pragma unroll
  for (int mt = 0; mt < 2; ++mt)
#pragma unroll
    for (int nt = 0; nt < NT; ++nt)
#pragma unroll
      for (int reg = 0; reg < 4; ++reg) {
        int row = mbase + mt * 16 + quad * 4 + reg;
        if (row < M) Cout[(size_t)row * N + nt * 16 + lc] = f2bf(acc[mt][nt][reg]);
      }
}

// ------------------ aggregation (latency-optimized gather) -----------------
// One node per G = F/2 lanes; each lane owns one dword (2 bf16 feats).
// 16-deep edge batching: 16 CSR entries -> 16 independent gathers in flight
// -> accumulate. Block 256 threads = 256/G nodes.
template <int F>
__global__ __launch_bounds__(256) void agg_fast_kernel(
    const unsigned short* __restrict__ xw, const int* __restrict__ offs,
    const unsigned int* __restrict__ csr, const float* __restrict__ dinv,
    const float* __restrict__ bias, const float* __restrict__ gamma,
    const float* __restrict__ beta, const float* __restrict__ mean,
    const float* __restrict__ var, unsigned short* __restrict__ out, int N) {
  constexpr int G = F / 2;
  constexpr int NPB = 256 / G;
  const int li = threadIdx.x % G;
  const int i = blockIdx.x * NPB + threadIdx.x / G;
  if (i >= N) return;
  const unsigned int* xw32 = (const unsigned int*)xw;
  const float di = dinv[i];
  const int s = offs[i], e = offs[i + 1];
  float accL = 0.f, accH = 0.f;
  int t = s;
  for (; t + 16 <= e; t += 16) {
    unsigned int ent[16];
#pragma unroll
    for (int j = 0; j < 16; ++j) ent[j] = csr[t + j];
    unsigned int gv[16];
#pragma unroll
    for (int j = 0; j < 16; ++j) gv[j] = xw32[(size_t)(ent[j] & 0xFFFFu) * G + li];
#pragma unroll
    for (int j = 0; j < 16; ++j) {
      float w = __uint_as_float(ent[j] & 0xFFFF0000u);
      accL += w * __uint_as_float(gv[j] << 16);
      accH += w * __uint_as_float(gv[j] & 0xFFFF0000u);
    }
  }
  for (; t + 4 <= e; t += 4) {
    unsigned int ent[4];
#pragma unroll
    for (int j = 0; j < 4; ++j) ent[j] = csr[t + j];
    unsigned int gv[4];
#pragma unroll
    for (int j = 0; j < 4; ++j) gv[j] = xw32[(size_t)(ent[j] & 0xFFFFu) * G + li];
#pragma unroll
    for (int j = 0; j < 4; ++j) {
      float w = __uint_as_float(ent[j] & 0xFFFF0000u);
      accL += w * __uint_as_float(gv[j] << 16);
      accH += w * __uint_as_float(gv[j] & 0xFFFF0000u);
    }
  }
  for (; t < e; ++t) {
    unsigned int ee = csr[t];
    unsigned int gv = xw32[(size_t)(ee & 0xFFFFu) * G + li];
    float w = __uint_as_float(ee & 0xFFFF0000u);
    accL += w * __uint_as_float(gv << 16);
    accH += w * __uint_as_float(gv & 0xFFFF0000u);
  }
  const int f0 = 2 * li, f1 = f0 + 1;
  unsigned int sv = xw32[(size_t)i * G + li];
  float v0 = di * accL + di * di * __uint_as_float(sv << 16) + bias[f0];
  float v1 = di * accH + di * di * __uint_as_float(sv & 0xFFFF0000u) + bias[f1];
  v0 = (v0 - mean[f0]) * rsqrtf(var[f0] + 1e-5f) * gamma[f0] + beta[f0];
  v1 = (v1 - mean[f1]) * rsqrtf(var[f1] + 1e-5f) * gamma[f1] + beta[f1];
  unsigned int packed =
      (unsigned int)f2bf(fmaxf(v0, 0.f)) | ((unsigned int)f2bf(fmaxf(v1, 0.f)) << 16);
  ((unsigned int*)out)[(size_t)i * G + li] = packed;
}

// ------------------------------- edge head ---------------------------------
__global__ __launch_bounds__(256) void head_mfma_kernel(
    const unsigned short* __restrict__ z, const int* __restrict__ src,
    const int* __restrict__ dst, const unsigned short* __restrict__ bfragH,
    const float* __restrict__ hb1, const float* __restrict__ hw2,
    const float* __restrict__ hb2, float* __restrict__ out, int P) {
  const int lane = threadIdx.x & 63;
  const int quad = lane >> 4;
  const int lc = lane & 15;

  short8x bf[4][4];
#pragma unroll
  for (int nt = 0; nt < 4; ++nt)
#pragma unroll
    for (int ks = 0; ks < 4; ++ks)
      bf[nt][ks] = *(const short8x*)(bfragH + (((size_t)nt * 4 + ks) * 64 + lane) * 8);

  float b1v[4], w2v[4];
#pragma unroll
  for (int nt = 0; nt < 4; ++nt) {
    b1v[nt] = hb1[nt * 16 + lc];
    w2v[nt] = hw2[nt * 16 + lc];
  }
  const float bias2 = hb2[0];

  const int nchunks = (P + 15) / 16;
  const int gw = blockIdx.x * 4 + (threadIdx.x >> 6);
  const int nw = gridDim.x * 4;

  for (int ch = gw; ch < nchunks; ch += nw) {
    int p = ch * 16 + lc;
    int pc = p < P ? p : P - 1;
    int s = src[pc], d = dst[pc];
    const unsigned short* zs = z + (size_t)s * 64;
    const unsigned short* zd = z + (size_t)d * 64;
    short8x a[4];
    a[0] = *(const short8x*)(zs + quad * 8);
    a[1] = *(const short8x*)(zs + 32 + quad * 8);
    a[2] = *(const short8x*)(zd + quad * 8);
    a[3] = *(const short8x*)(zd + 32 + quad * 8);

    f32x4 acc[4];
#pragma unroll
    for (int nt = 0; nt < 4; ++nt) acc[nt] = (f32x4){0.f, 0.f, 0.f, 0.f};
#pragma unroll
    for (int nt = 0; nt < 4; ++nt)
#pragma unroll
      for (int t = 0; t < 4; ++t)
        acc[nt] = __builtin_amdgcn_mfma_f32_16x16x32_bf16(a[t], bf[nt][t], acc[nt], 0, 0, 0);

    float part[4];
#pragma unroll
    for (int reg = 0; reg < 4; ++reg) {
      float sum = 0.f;
#pragma unroll
      for (int nt = 0; nt < 4; ++nt) sum += fmaxf(acc[nt][reg] + b1v[nt], 0.f) * w2v[nt];
      part[reg] = sum;
    }
#pragma unroll
    for (int m = 1; m < 16; m <<= 1) {
#pragma unroll
      for (int reg = 0; reg < 4; ++reg) part[reg] += __shfl_xor(part[reg], m, 64);
    }
    if (lc == 0) {
      int pbase = ch * 16 + quad * 4;
      float4 o;
      o.x = 1.0f / (1.0f + __expf(-(part[0] + bias2)));
      o.y = 1.0f / (1.0f + __expf(-(part[1] + bias2)));
      o.z = 1.0f / (1.0f + __expf(-(part[2] + bias2)));
      o.w = 1.0f / (1.0f + __expf(-(part[3] + bias2)));
      if (pbase + 3 < P) {
        *(float4*)(out + pbase) = o;
      } else {
        float ov[4] = {o.x, o.y, o.z, o.w};
        for (int reg = 0; reg < 4; ++reg)
          if (pbase + reg < P) out[pbase + reg] = ov[reg];
      }
    }
  }
}

// ------------------------------- launcher ----------------------------------

extern "C" void kernel_launch(void* const* d_in, const int* in_sizes, int n_in,
                              void* d_out, int out_size, void* d_ws, size_t ws_size,
                              hipStream_t stream) {
  const float* x = (const float*)d_in[0];
  const int* ei = (const int*)d_in[1];
  const int* src = (const int*)d_in[2];
  const int* dst = (const int*)d_in[3];
  const float* W1 = (const float*)d_in[4];
  const float* b1 = (const float*)d_in[5];
  const float* g1 = (const float*)d_in[6];
  const float* be1 = (const float*)d_in[7];
  const float* mu1 = (const float*)d_in[8];
  const float* va1 = (const float*)d_in[9];
  const float* W2 = (const float*)d_in[10];
  const float* b2 = (const float*)d_in[11];
  const float* g2 = (const float*)d_in[12];
  const float* be2 = (const float*)d_in[13];
  const float* mu2 = (const float*)d_in[14];
  const float* va2 = (const float*)d_in[15];
  const float* hW1 = (const float*)d_in[16];
  const float* hb1 = (const float*)d_in[17];
  const float* hW2 = (const float*)d_in[18];
  const float* hb2 = (const float*)d_in[19];
  float* out = (float*)d_out;

  const int N = in_sizes[0] / 512;
  const int E = in_sizes[1] / 2;
  const int P = in_sizes[2];
  const int* row = ei;
  const int* col = ei + E;
  const int NBK = (N + 255) / 256;    // scatter buckets (256 nodes each)
  const int NSB = (N + 1023) / 1024;  // scan blocks
  const int NAB = (E + 4095) / 4096;  // binA blocks

  char* wp = (char*)d_ws;
  auto alloc = [&](size_t bytes) {
    char* p = wp;
    wp += (bytes + 255) & ~(size_t)255;
    return p;
  };
  unsigned short* xw1 = (unsigned short*)alloc((size_t)N * 128 * 2);
  unsigned short* h = (unsigned short*)alloc((size_t)N * 128 * 2);
  unsigned short* xw2 = (unsigned short*)alloc((size_t)N * 64 * 2);
  unsigned short* z = (unsigned short*)alloc((size_t)N * 64 * 2);
  float* dinv = (float*)alloc((size_t)N * 4);
  int* deg = (int*)alloc((size_t)N * 4);
  int* offs = (int*)alloc((size_t)(N + 1) * 4);
  unsigned int* csr = (unsigned int*)alloc((size_t)E * 4);
  unsigned int* staging = (unsigned int*)alloc((size_t)E * 4);
  int* bsum = (int*)alloc((size_t)NSB * 4);
  int* bcur = (int*)alloc((size_t)NBK * 4);
  int* total = (int*)alloc(256);
  unsigned short* bfW1 = (unsigned short*)alloc(512 * 128 * 2);
  unsigned short* bfW2 = (unsigned short*)alloc(128 * 64 * 2);
  unsigned short* bfH = (unsigned short*)alloc(128 * 64 * 2);
  (void)ws_size;
  (void)n_in;
  (void)out_size;

  // --- graph structure ---
  hipLaunchKernelGGL(zero_int_kernel, dim3((N + 255) / 256), dim3(256), 0, stream, deg, N);
  hipLaunchKernelGGL(degree_hist_kernel, dim3((E + 255) / 256), dim3(256), 0, stream, col, deg, E);
  hipLaunchKernelGGL(scan_blocksum_kernel, dim3(NSB), dim3(256), 0, stream, deg, bsum, N);
  hipLaunchKernelGGL(scan_bsum_kernel, dim3(1), dim3(64), 0, stream, bsum, NSB, total);
  hipLaunchKernelGGL(scan_final_kernel, dim3(NSB), dim3(256), 0, stream, deg, bsum, offs, dinv, N);
  hipLaunchKernelGGL(bucket_init_kernel, dim3((NBK + 255) / 256), dim3(256), 0, stream, offs, total,
                     bcur, offs + N, NBK);
  hipLaunchKernelGGL(binA_kernel, dim3(NAB), dim3(256), 0, stream, row, col, bcur, staging, E, NBK);
  hipLaunchKernelGGL(binB_kernel, dim3(NBK), dim3(512), 0, stream, staging, offs, dinv, csr, N);

  // --- weight fragment prep ---
  hipLaunchKernelGGL(prep_bfrag_kernel, dim3((8 * 16 * 64 + 255) / 256), dim3(256), 0, stream, W1,
                     bfW1, 512, 128);
  hipLaunchKernelGGL(prep_bfrag_kernel, dim3((4 * 4 * 64 + 255) / 256), dim3(256), 0, stream, W2,
                     bfW2, 128, 64);
  hipLaunchKernelGGL(prep_bfrag_kernel, dim3((4 * 4 * 64 + 255) / 256), dim3(256), 0, stream, hW1,
                     bfH, 128, 64);

  // --- layer 1 ---
  hipLaunchKernelGGL((mfma_gemm_kernel<512, 128, false>), dim3((N + 127) / 128), dim3(256), 0,
                     stream, x, bfW1, xw1, N);
  hipLaunchKernelGGL((agg_fast_kernel<128>), dim3((N + 3) / 4), dim3(256), 0, stream, xw1, offs,
                     csr, dinv, b1, g1, be1, mu1, va1, h, N);

  // --- layer 2 ---
  hipLaunchKernelGGL((mfma_gemm_kernel<128, 64, true>), dim3((N + 127) / 128), dim3(256), 0, stream,
                     h, bfW2, xw2, N);
  hipLaunchKernelGGL((agg_fast_kernel<64>), dim3((N + 7) / 8), dim3(256), 0, stream, xw2, offs,
                     csr, dinv, b2, g2, be2, mu2, va2, z, N);

  // --- edge head ---
  hipLaunchKernelGGL(head_mfma_kernel, dim3(2048), dim3(256), 0, stream, z, src, dst, bfH, hb1,
                     hW2, hb2, out, P);
}

// Round 8
// 387.161 us; speedup vs baseline: 1.8434x; 1.1340x over previous
//
#include <hip/hip_runtime.h>
#include <math.h>

// ---------------------------------------------------------------------------
// GCN link predictor on MI355X, round 8.
// Round-7 post-mortem: degree_hist (1.6M device atomics over 50k counters)
// was 70us with 50MB HBM write-back. Round 8 derives per-node degrees from
// the bucketed staging array instead:
//   binA_hist (196-bucket LDS hist, 77k global atomics) -> scan_buckets ->
//   binA_scatter -> binB1 (per-bucket LDS node-hist + scan -> offs, dinv)
//   -> binB2 (fine scatter, CSR = bf16(dinv[row])<<16 | row).
// Aggregation: 16-deep MLP-batched gather (round-7 WIN). GEMMs/head: MFMA.
// ---------------------------------------------------------------------------

typedef __attribute__((ext_vector_type(8))) short short8x;
typedef __attribute__((ext_vector_type(4))) float f32x4;

__device__ __forceinline__ unsigned short f2bf(float f) {
  unsigned int u = __float_as_uint(f);
  unsigned int r = u + 0x7FFFu + ((u >> 16) & 1u);  // RNE
  return (unsigned short)(r >> 16);
}
__device__ __forceinline__ float bf2f(unsigned short u) {
  return __uint_as_float(((unsigned int)u) << 16);
}

// ------------------------------ graph build --------------------------------

__global__ void zero_int_kernel(int* __restrict__ p, int n) {
  int i = blockIdx.x * blockDim.x + threadIdx.x;
  if (i < n) p[i] = 0;
}

// Per-block LDS histogram over buckets (col>>8); one global atomic per
// (block,bucket). 4096 edges/block.
__global__ __launch_bounds__(256) void binA_hist_kernel(const int* __restrict__ col,
                                                        int* __restrict__ bucket_count, int E,
                                                        int NBK) {
  __shared__ int hist[256];
  const int tid = threadIdx.x;
  hist[tid] = 0;
  __syncthreads();
  const int base = blockIdx.x * 4096;
#pragma unroll
  for (int j = 0; j < 16; ++j) {
    int i = base + j * 256 + tid;
    if (i < E) atomicAdd(&hist[((unsigned int)col[i]) >> 8], 1);
  }
  __syncthreads();
  if (tid < NBK) {
    int h = hist[tid];
    if (h) atomicAdd(&bucket_count[tid], h);
  }
}

// Single block: exclusive scan of NBK (<=256) bucket counts.
// Writes bucket_start[0..NBK], bcur, and offs[N] = E.
__global__ __launch_bounds__(256) void scan_buckets_kernel(const int* __restrict__ bucket_count,
                                                           int* __restrict__ bucket_start,
                                                           int* __restrict__ bcur,
                                                           int* __restrict__ offs_n, int NBK,
                                                           int E) {
  __shared__ int ws[4];
  const int tid = threadIdx.x;
  const int lane = tid & 63;
  const int wid = tid >> 6;
  int v = (tid < NBK) ? bucket_count[tid] : 0;
  int incl = v;
#pragma unroll
  for (int d = 1; d < 64; d <<= 1) {
    int t = __shfl_up(incl, d, 64);
    if (lane >= d) incl += t;
  }
  if (lane == 63) ws[wid] = incl;
  __syncthreads();
  int woff = 0;
#pragma unroll
  for (int w = 0; w < 4; ++w)
    if (w < wid) woff += ws[w];
  int excl = woff + incl - v;
  if (tid < NBK) {
    bucket_start[tid] = excl;
    bcur[tid] = excl;
  }
  if (tid == 0) {
    bucket_start[NBK] = E;
    *offs_n = E;
  }
}

// binA_scatter: 4096 edges/block; LDS hist -> one global atomicAdd per
// (block,bucket) reserve -> LDS-cursor scatter of packed (col<<16|row).
__global__ __launch_bounds__(256) void binA_scatter_kernel(const int* __restrict__ row,
                                                           const int* __restrict__ col,
                                                           int* __restrict__ bcur,
                                                           unsigned int* __restrict__ staging,
                                                           int E, int NBK) {
  __shared__ int hist[256];
  const int tid = threadIdx.x;
  hist[tid] = 0;
  __syncthreads();
  const int base = blockIdx.x * 4096;
  unsigned int payload[16];
  int bk[16];
#pragma unroll
  for (int j = 0; j < 16; ++j) {
    int i = base + j * 256 + tid;
    if (i < E) {
      unsigned int c = (unsigned int)col[i];
      unsigned int r = (unsigned int)row[i];
      payload[j] = (c << 16) | r;
      bk[j] = (int)(c >> 8);
      atomicAdd(&hist[bk[j]], 1);
    } else {
      bk[j] = -1;
    }
  }
  __syncthreads();
  if (tid < NBK) {
    int h = hist[tid];
    hist[tid] = h ? atomicAdd(&bcur[tid], h) : 0;
  }
  __syncthreads();
#pragma unroll
  for (int j = 0; j < 16; ++j) {
    if (bk[j] >= 0) {
      int p = atomicAdd(&hist[bk[j]], 1);
      staging[p] = payload[j];
    }
  }
}

// binB1: one block per 256-node bucket. LDS node-histogram of the bucket's
// staging segment -> LDS scan -> writes offs[node] and dinv[node].
__global__ __launch_bounds__(256) void binB1_kernel(const unsigned int* __restrict__ staging,
                                                    const int* __restrict__ bucket_start,
                                                    int* __restrict__ offs,
                                                    float* __restrict__ dinv, int N) {
  __shared__ int cnt[256];
  __shared__ int ws[4];
  const int b = blockIdx.x;
  const int n0 = b * 256;
  const int tid = threadIdx.x;
  cnt[tid] = 0;
  __syncthreads();
  const int s = bucket_start[b];
  const int e = bucket_start[b + 1];
  for (int t = s + tid; t < e; t += 256) {
    atomicAdd(&cnt[(staging[t] >> 16) & 255u], 1);
  }
  __syncthreads();
  const int deg = cnt[tid];
  const int lane = tid & 63;
  const int wid = tid >> 6;
  int incl = deg;
#pragma unroll
  for (int d = 1; d < 64; d <<= 1) {
    int t = __shfl_up(incl, d, 64);
    if (lane >= d) incl += t;
  }
  if (lane == 63) ws[wid] = incl;
  __syncthreads();
  int woff = 0;
#pragma unroll
  for (int w = 0; w < 4; ++w)
    if (w < wid) woff += ws[w];
  const int excl = woff + incl - deg;
  const int node = n0 + tid;
  if (node < N) {
    offs[node] = s + excl;
    dinv[node] = rsqrtf((float)deg + 1.0f);
  }
}

// binB2: fine scatter into CSR with packed bf16 dinv (dinv fully written by
// binB1 before this kernel launches).
__global__ __launch_bounds__(512) void binB2_kernel(const unsigned int* __restrict__ staging,
                                                    const int* __restrict__ offs,
                                                    const int* __restrict__ bucket_start,
                                                    const float* __restrict__ dinv,
                                                    unsigned int* __restrict__ csr, int N) {
  __shared__ int cur[256];
  const int b = blockIdx.x;
  const int n0 = b * 256;
  const int tid = threadIdx.x;
  if (tid < 256 && n0 + tid < N) cur[tid] = offs[n0 + tid];
  __syncthreads();
  const int s = bucket_start[b];
  const int e = bucket_start[b + 1];
  for (int t = s + tid; t < e; t += 512) {
    unsigned int v = __builtin_nontemporal_load(&staging[t]);
    int cl = (int)((v >> 16) & 255u);
    unsigned int r = v & 0xFFFFu;
    unsigned int wd = f2bf(dinv[r]);
    int p = atomicAdd(&cur[cl], 1);
    csr[p] = (wd << 16) | r;
  }
}

// --------------------- weight prep: fragment ordering ----------------------
__global__ void prep_bfrag_kernel(const float* __restrict__ W, unsigned short* __restrict__ out,
                                  int K, int N) {
  int idx = blockIdx.x * blockDim.x + threadIdx.x;
  int KS = K / 32;
  int total = (N / 16) * KS * 64;
  if (idx >= total) return;
  int lane = idx & 63;
  int t = idx >> 6;
  int ks = t % KS;
  int nt = t / KS;
  int n = nt * 16 + (lane & 15);
  int k0 = ks * 32 + (lane >> 4) * 8;
  unsigned short* o = out + (size_t)idx * 8;
#pragma unroll
  for (int j = 0; j < 8; ++j) o[j] = f2bf(W[(size_t)(k0 + j) * N + n]);
}

// ------------------------------- MFMA GEMM ---------------------------------
template <int K, int N, bool ABF16>
__global__ __launch_bounds__(256) void mfma_gemm_kernel(const void* __restrict__ Ap,
                                                        const unsigned short* __restrict__ Bfrag,
                                                        unsigned short* __restrict__ Cout, int M) {
  constexpr int KS = K / 32;
  constexpr int NT = N / 16;
  const int lane = threadIdx.x & 63;
  const int wid = threadIdx.x >> 6;
  const int quad = lane >> 4;
  const int lc = lane & 15;
  const int mbase = blockIdx.x * 128 + wid * 32;
  if (mbase >= M) return;

  f32x4 acc[2][NT];
#pragma unroll
  for (int mt = 0; mt < 2; ++mt)
#pragma unroll
    for (int nt = 0; nt < NT; ++nt) acc[mt][nt] = (f32x4){0.f, 0.f, 0.f, 0.f};

  int r0 = mbase + lc;
  int r1 = mbase + 16 + lc;
  if (r0 >= M) r0 = M - 1;
  if (r1 >= M) r1 = M - 1;

#pragma unroll
  for (int ks = 0; ks < KS; ++ks) {
    const int k0 = ks * 32 + quad * 8;
    short8x a[2];
    if constexpr (ABF16) {
      const unsigned short* A = (const unsigned short*)Ap;
      a[0] = *(const short8x*)(A + (size_t)r0 * K + k0);
      a[1] = *(const short8x*)(A + (size_t)r1 * K + k0);
    } else {
      const float* A = (const float*)Ap;
      const float4* p0 = (const float4*)(A + (size_t)r0 * K + k0);
      const float4* p1 = (const float4*)(A + (size_t)r1 * K + k0);
      float4 u0 = p0[0], v0 = p0[1];
      float4 u1 = p1[0], v1 = p1[1];
      short8x t0, t1;
      t0[0] = (short)f2bf(u0.x); t0[1] = (short)f2bf(u0.y);
      t0[2] = (short)f2bf(u0.z); t0[3] = (short)f2bf(u0.w);
      t0[4] = (short)f2bf(v0.x); t0[5] = (short)f2bf(v0.y);
      t0[6] = (short)f2bf(v0.z); t0[7] = (short)f2bf(v0.w);
      t1[0] = (short)f2bf(u1.x); t1[1] = (short)f2bf(u1.y);
      t1[2] = (short)f2bf(u1.z); t1[3] = (short)f2bf(u1.w);
      t1[4] = (short)f2bf(v1.x); t1[5] = (short)f2bf(v1.y);
      t1[6] = (short)f2bf(v1.z); t1[7] = (short)f2bf(v1.w);
      a[0] = t0;
      a[1] = t1;
    }
#pragma unroll
    for (int nt = 0; nt < NT; ++nt) {
      short8x b = *(const short8x*)(Bfrag + (((size_t)nt * KS + ks) * 64 + lane) * 8);
      acc[0][nt] = __builtin_amdgcn_mfma_f32_16x16x32_bf16(a[0], b, acc[0][nt], 0, 0, 0);
      acc[1][nt] = __builtin_amdgcn_mfma_f32_16x16x32_bf16(a[1], b, acc[1][nt], 0, 0, 0);
    }
  }

#pragma unroll
  for (int mt = 0; mt < 2; ++mt)
#pragma unroll
    for (int nt = 0; nt < NT; ++nt)
#pragma unroll
      for (int reg = 0; reg < 4; ++reg) {
        int row = mbase + mt * 16 + quad * 4 + reg;
        if (row < M) Cout[(size_t)row * N + nt * 16 + lc] = f2bf(acc[mt][nt][reg]);
      }
}

// ------------------ aggregation (latency-optimized gather) -----------------
// One node per G = F/2 lanes; each lane owns one dword (2 bf16 feats).
// 16-deep edge batching keeps 16 independent gathers in flight per lane.
template <int F>
__global__ __launch_bounds__(256) void agg_fast_kernel(
    const unsigned short* __restrict__ xw, const int* __restrict__ offs,
    const unsigned int* __restrict__ csr, const float* __restrict__ dinv,
    const float* __restrict__ bias, const float* __restrict__ gamma,
    const float* __restrict__ beta, const float* __restrict__ mean,
    const float* __restrict__ var, unsigned short* __restrict__ out, int N) {
  constexpr int G = F / 2;
  constexpr int NPB = 256 / G;
  const int li = threadIdx.x % G;
  const int i = blockIdx.x * NPB + threadIdx.x / G;
  if (i >= N) return;
  const unsigned int* xw32 = (const unsigned int*)xw;
  const float di = dinv[i];
  const int s = offs[i], e = offs[i + 1];
  float accL = 0.f, accH = 0.f;
  int t = s;
  for (; t + 16 <= e; t += 16) {
    unsigned int ent[16];
#pragma unroll
    for (int j = 0; j < 16; ++j) ent[j] = csr[t + j];
    unsigned int gv[16];
#pragma unroll
    for (int j = 0; j < 16; ++j) gv[j] = xw32[(size_t)(ent[j] & 0xFFFFu) * G + li];
#pragma unroll
    for (int j = 0; j < 16; ++j) {
      float w = __uint_as_float(ent[j] & 0xFFFF0000u);
      accL += w * __uint_as_float(gv[j] << 16);
      accH += w * __uint_as_float(gv[j] & 0xFFFF0000u);
    }
  }
  for (; t + 4 <= e; t += 4) {
    unsigned int ent[4];
#pragma unroll
    for (int j = 0; j < 4; ++j) ent[j] = csr[t + j];
    unsigned int gv[4];
#pragma unroll
    for (int j = 0; j < 4; ++j) gv[j] = xw32[(size_t)(ent[j] & 0xFFFFu) * G + li];
#pragma unroll
    for (int j = 0; j < 4; ++j) {
      float w = __uint_as_float(ent[j] & 0xFFFF0000u);
      accL += w * __uint_as_float(gv[j] << 16);
      accH += w * __uint_as_float(gv[j] & 0xFFFF0000u);
    }
  }
  for (; t < e; ++t) {
    unsigned int ee = csr[t];
    unsigned int gv = xw32[(size_t)(ee & 0xFFFFu) * G + li];
    float w = __uint_as_float(ee & 0xFFFF0000u);
    accL += w * __uint_as_float(gv << 16);
    accH += w * __uint_as_float(gv & 0xFFFF0000u);
  }
  const int f0 = 2 * li, f1 = f0 + 1;
  unsigned int sv = xw32[(size_t)i * G + li];
  float v0 = di * accL + di * di * __uint_as_float(sv << 16) + bias[f0];
  float v1 = di * accH + di * di * __uint_as_float(sv & 0xFFFF0000u) + bias[f1];
  v0 = (v0 - mean[f0]) * rsqrtf(var[f0] + 1e-5f) * gamma[f0] + beta[f0];
  v1 = (v1 - mean[f1]) * rsqrtf(var[f1] + 1e-5f) * gamma[f1] + beta[f1];
  unsigned int packed =
      (unsigned int)f2bf(fmaxf(v0, 0.f)) | ((unsigned int)f2bf(fmaxf(v1, 0.f)) << 16);
  ((unsigned int*)out)[(size_t)i * G + li] = packed;
}

// ------------------------------- edge head ---------------------------------
__global__ __launch_bounds__(256) void head_mfma_kernel(
    const unsigned short* __restrict__ z, const int* __restrict__ src,
    const int* __restrict__ dst, const unsigned short* __restrict__ bfragH,
    const float* __restrict__ hb1, const float* __restrict__ hw2,
    const float* __restrict__ hb2, float* __restrict__ out, int P) {
  const int lane = threadIdx.x & 63;
  const int quad = lane >> 4;
  const int lc = lane & 15;

  short8x bf[4][4];
#pragma unroll
  for (int nt = 0; nt < 4; ++nt)
#pragma unroll
    for (int ks = 0; ks < 4; ++ks)
      bf[nt][ks] = *(const short8x*)(bfragH + (((size_t)nt * 4 + ks) * 64 + lane) * 8);

  float b1v[4], w2v[4];
#pragma unroll
  for (int nt = 0; nt < 4; ++nt) {
    b1v[nt] = hb1[nt * 16 + lc];
    w2v[nt] = hw2[nt * 16 + lc];
  }
  const float bias2 = hb2[0];

  const int nchunks = (P + 15) / 16;
  const int gw = blockIdx.x * 4 + (threadIdx.x >> 6);
  const int nw = gridDim.x * 4;

  for (int ch = gw; ch < nchunks; ch += nw) {
    int p = ch * 16 + lc;
    int pc = p < P ? p : P - 1;
    int s = src[pc], d = dst[pc];
    const unsigned short* zs = z + (size_t)s * 64;
    const unsigned short* zd = z + (size_t)d * 64;
    short8x a[4];
    a[0] = *(const short8x*)(zs + quad * 8);
    a[1] = *(const short8x*)(zs + 32 + quad * 8);
    a[2] = *(const short8x*)(zd + quad * 8);
    a[3] = *(const short8x*)(zd + 32 + quad * 8);

    f32x4 acc[4];
#pragma unroll
    for (int nt = 0; nt < 4; ++nt) acc[nt] = (f32x4){0.f, 0.f, 0.f, 0.f};
#pragma unroll
    for (int nt = 0; nt < 4; ++nt)
#pragma unroll
      for (int t = 0; t < 4; ++t)
        acc[nt] = __builtin_amdgcn_mfma_f32_16x16x32_bf16(a[t], bf[nt][t], acc[nt], 0, 0, 0);

    float part[4];
#pragma unroll
    for (int reg = 0; reg < 4; ++reg) {
      float sum = 0.f;
#pragma unroll
      for (int nt = 0; nt < 4; ++nt) sum += fmaxf(acc[nt][reg] + b1v[nt], 0.f) * w2v[nt];
      part[reg] = sum;
    }
#pragma unroll
    for (int m = 1; m < 16; m <<= 1) {
#pragma unroll
      for (int reg = 0; reg < 4; ++reg) part[reg] += __shfl_xor(part[reg], m, 64);
    }
    if (lc == 0) {
      int pbase = ch * 16 + quad * 4;
      float4 o;
      o.x = 1.0f / (1.0f + __expf(-(part[0] + bias2)));
      o.y = 1.0f / (1.0f + __expf(-(part[1] + bias2)));
      o.z = 1.0f / (1.0f + __expf(-(part[2] + bias2)));
      o.w = 1.0f / (1.0f + __expf(-(part[3] + bias2)));
      if (pbase + 3 < P) {
        *(float4*)(out + pbase) = o;
      } else {
        float ov[4] = {o.x, o.y, o.z, o.w};
        for (int reg = 0; reg < 4; ++reg)
          if (pbase + reg < P) out[pbase + reg] = ov[reg];
      }
    }
  }
}

// ------------------------------- launcher ----------------------------------

extern "C" void kernel_launch(void* const* d_in, const int* in_sizes, int n_in,
                              void* d_out, int out_size, void* d_ws, size_t ws_size,
                              hipStream_t stream) {
  const float* x = (const float*)d_in[0];
  const int* ei = (const int*)d_in[1];
  const int* src = (const int*)d_in[2];
  const int* dst = (const int*)d_in[3];
  const float* W1 = (const float*)d_in[4];
  const float* b1 = (const float*)d_in[5];
  const float* g1 = (const float*)d_in[6];
  const float* be1 = (const float*)d_in[7];
  const float* mu1 = (const float*)d_in[8];
  const float* va1 = (const float*)d_in[9];
  const float* W2 = (const float*)d_in[10];
  const float* b2 = (const float*)d_in[11];
  const float* g2 = (const float*)d_in[12];
  const float* be2 = (const float*)d_in[13];
  const float* mu2 = (const float*)d_in[14];
  const float* va2 = (const float*)d_in[15];
  const float* hW1 = (const float*)d_in[16];
  const float* hb1 = (const float*)d_in[17];
  const float* hW2 = (const float*)d_in[18];
  const float* hb2 = (const float*)d_in[19];
  float* out = (float*)d_out;

  const int N = in_sizes[0] / 512;
  const int E = in_sizes[1] / 2;
  const int P = in_sizes[2];
  const int* row = ei;
  const int* col = ei + E;
  const int NBK = (N + 255) / 256;    // buckets (256 nodes each), <=256
  const int NAB = (E + 4095) / 4096;  // binA blocks

  char* wp = (char*)d_ws;
  auto alloc = [&](size_t bytes) {
    char* p = wp;
    wp += (bytes + 255) & ~(size_t)255;
    return p;
  };
  unsigned short* xw1 = (unsigned short*)alloc((size_t)N * 128 * 2);
  unsigned short* h = (unsigned short*)alloc((size_t)N * 128 * 2);
  unsigned short* xw2 = (unsigned short*)alloc((size_t)N * 64 * 2);
  unsigned short* z = (unsigned short*)alloc((size_t)N * 64 * 2);
  float* dinv = (float*)alloc((size_t)N * 4);
  int* offs = (int*)alloc((size_t)(N + 1) * 4);
  unsigned int* csr = (unsigned int*)alloc((size_t)E * 4);
  unsigned int* staging = (unsigned int*)alloc((size_t)E * 4);
  int* bucket_count = (int*)alloc((size_t)NBK * 4);
  int* bucket_start = (int*)alloc((size_t)(NBK + 1) * 4);
  int* bcur = (int*)alloc((size_t)NBK * 4);
  unsigned short* bfW1 = (unsigned short*)alloc(512 * 128 * 2);
  unsigned short* bfW2 = (unsigned short*)alloc(128 * 64 * 2);
  unsigned short* bfH = (unsigned short*)alloc(128 * 64 * 2);
  (void)ws_size;
  (void)n_in;
  (void)out_size;

  // --- graph structure (no per-node global atomics anywhere) ---
  hipLaunchKernelGGL(zero_int_kernel, dim3((NBK + 255) / 256), dim3(256), 0, stream, bucket_count,
                     NBK);
  hipLaunchKernelGGL(binA_hist_kernel, dim3(NAB), dim3(256), 0, stream, col, bucket_count, E, NBK);
  hipLaunchKernelGGL(scan_buckets_kernel, dim3(1), dim3(256), 0, stream, bucket_count,
                     bucket_start, bcur, offs + N, NBK, E);
  hipLaunchKernelGGL(binA_scatter_kernel, dim3(NAB), dim3(256), 0, stream, row, col, bcur, staging,
                     E, NBK);
  hipLaunchKernelGGL(binB1_kernel, dim3(NBK), dim3(256), 0, stream, staging, bucket_start, offs,
                     dinv, N);
  hipLaunchKernelGGL(binB2_kernel, dim3(NBK), dim3(512), 0, stream, staging, offs, bucket_start,
                     dinv, csr, N);

  // --- weight fragment prep ---
  hipLaunchKernelGGL(prep_bfrag_kernel, dim3((8 * 16 * 64 + 255) / 256), dim3(256), 0, stream, W1,
                     bfW1, 512, 128);
  hipLaunchKernelGGL(prep_bfrag_kernel, dim3((4 * 4 * 64 + 255) / 256), dim3(256), 0, stream, W2,
                     bfW2, 128, 64);
  hipLaunchKernelGGL(prep_bfrag_kernel, dim3((4 * 4 * 64 + 255) / 256), dim3(256), 0, stream, hW1,
                     bfH, 128, 64);

  // --- layer 1 ---
  hipLaunchKernelGGL((mfma_gemm_kernel<512, 128, false>), dim3((N + 127) / 128), dim3(256), 0,
                     stream, x, bfW1, xw1, N);
  hipLaunchKernelGGL((agg_fast_kernel<128>), dim3((N + 3) / 4), dim3(256), 0, stream, xw1, offs,
                     csr, dinv, b1, g1, be1, mu1, va1, h, N);

  // --- layer 2 ---
  hipLaunchKernelGGL((mfma_gemm_kernel<128, 64, true>), dim3((N + 127) / 128), dim3(256), 0, stream,
                     h, bfW2, xw2, N);
  hipLaunchKernelGGL((agg_fast_kernel<64>), dim3((N + 7) / 8), dim3(256), 0, stream, xw2, offs,
                     csr, dinv, b2, g2, be2, mu2, va2, z, N);

  // --- edge head ---
  hipLaunchKernelGGL(head_mfma_kernel, dim3(2048), dim3(256), 0, stream, z, src, dst, bfH, hb1,
                     hW2, hb2, out, P);
}